// Round 1
// baseline (908.370 us; speedup 1.0000x reference)
//
#include <hip/hip_runtime.h>
#include <hip/hip_bf16.h>

typedef __attribute__((ext_vector_type(8))) short bf16x8;
typedef __attribute__((ext_vector_type(4))) float f32x4;

#define BM 128
#define BN 128
#define BK 64

#define GLDS(g, l) \
  __builtin_amdgcn_global_load_lds((const __attribute__((address_space(1))) void*)(g), \
                                   (__attribute__((address_space(3))) void*)(l), 16, 0, 0)

// ---------------- Kernel 1: X fp32 -> bf16 (vectorized, grid-stride) ----------------
__global__ __launch_bounds__(256) void k_cvt_bf16(const float* __restrict__ x,
                                                  __hip_bfloat16* __restrict__ y,
                                                  long n8) {
  long stride = (long)gridDim.x * blockDim.x;
  for (long i = (long)blockIdx.x * blockDim.x + threadIdx.x; i < n8; i += stride) {
    const float4* xin = reinterpret_cast<const float4*>(x) + i * 2;
    float4 v0 = xin[0];
    float4 v1 = xin[1];
    union { __hip_bfloat16 h[8]; int4 v; } o;
    o.h[0] = __float2bfloat16(v0.x);
    o.h[1] = __float2bfloat16(v0.y);
    o.h[2] = __float2bfloat16(v0.z);
    o.h[3] = __float2bfloat16(v0.w);
    o.h[4] = __float2bfloat16(v1.x);
    o.h[5] = __float2bfloat16(v1.y);
    o.h[6] = __float2bfloat16(v1.z);
    o.h[7] = __float2bfloat16(v1.w);
    *reinterpret_cast<int4*>(y + i * 8) = o.v;
  }
}

// ---------------- Kernel 2: assemble W bf16 ----------------
// W[o][c*64+d] = sum_r L[o*512 + c*8 + r] * R[((r*64+b)*64+c)*64 + d],  b = o & 63
__global__ __launch_bounds__(256) void k_make_w(const float* __restrict__ L,
                                                const float* __restrict__ R,
                                                __hip_bfloat16* __restrict__ W) {
  int o = blockIdx.x;
  int b = o & 63;
  __shared__ float Ls[512];
  Ls[threadIdx.x] = L[(size_t)o * 512 + threadIdx.x];
  Ls[threadIdx.x + 256] = L[(size_t)o * 512 + 256 + threadIdx.x];
  __syncthreads();
  for (int idx = threadIdx.x; idx < 4096; idx += 256) {
    int c = idx >> 6;
    int d = idx & 63;
    float s = 0.f;
#pragma unroll
    for (int r = 0; r < 8; ++r) {
      s += Ls[c * 8 + r] * R[(((size_t)(r * 64 + b) * 64 + c) << 6) + d];
    }
    W[(size_t)o * 4096 + idx] = __float2bfloat16(s);
  }
}

// ---------------- Kernel 3: bf16 GEMM, C = A * B^T + bias ----------------
// A: [M=16384][K=4096] bf16 row-major (X)
// B: [N=4096][K=4096] bf16 row-major (W, stored [out,in] so K-contiguous)
// C: [M][N] fp32, bias per column (out feature)
__global__ __launch_bounds__(256) void k_gemm_bt(const __hip_bfloat16* __restrict__ A,
                                                 const __hip_bfloat16* __restrict__ B,
                                                 const float* __restrict__ bias,
                                                 float* __restrict__ C) {
  const int K = 4096, N = 4096;
  __shared__ __hip_bfloat16 sA[BM * BK];
  __shared__ __hip_bfloat16 sB[BN * BK];

  const int tid = threadIdx.x;
  const int lane = tid & 63;
  const int wid = tid >> 6;
  const int wm = (wid >> 1) * 64;  // 2x2 waves, each owns 64x64
  const int wn = (wid & 1) * 64;
  const int bm = blockIdx.y, bn = blockIdx.x;

  // staging geometry: 16B chunks; chunk ci = it*256 + tid covers
  //   row = ci>>3, col = (ci&7)*8  of a [128][64] bf16 tile
  const int srow = tid >> 3;        // + it*32
  const int scol = (tid & 7) * 8;

  const __hip_bfloat16* Ab = A + (size_t)(bm * BM) * K;
  const __hip_bfloat16* Bb = B + (size_t)(bn * BN) * K;

  f32x4 acc[4][4];
#pragma unroll
  for (int m = 0; m < 4; ++m)
#pragma unroll
    for (int n = 0; n < 4; ++n) acc[m][n] = (f32x4){0.f, 0.f, 0.f, 0.f};

  for (int kt = 0; kt < K; kt += BK) {
    // ---- stage A and B tiles: 4 wave-wide global_load_lds each ----
#pragma unroll
    for (int it = 0; it < 4; ++it) {
      int r = it * 32 + srow;
      GLDS(Ab + (size_t)r * K + kt + scol, sA + (it * 256 + wid * 64) * 8);
    }
#pragma unroll
    for (int it = 0; it < 4; ++it) {
      int r = it * 32 + srow;
      GLDS(Bb + (size_t)r * K + kt + scol, sB + (it * 256 + wid * 64) * 8);
    }
    __syncthreads();  // drains vmcnt before barrier (compiler-inserted)

    // ---- compute: 2 x 16 MFMA ----
#pragma unroll
    for (int kk = 0; kk < 2; ++kk) {
      const int ko = kk * 32 + (lane >> 4) * 8;
      bf16x8 af[4], bfr[4];
#pragma unroll
      for (int m = 0; m < 4; ++m)
        af[m] = *(const bf16x8*)&sA[(wm + m * 16 + (lane & 15)) * BK + ko];
#pragma unroll
      for (int n = 0; n < 4; ++n)
        bfr[n] = *(const bf16x8*)&sB[(wn + n * 16 + (lane & 15)) * BK + ko];
#pragma unroll
      for (int m = 0; m < 4; ++m)
#pragma unroll
        for (int n = 0; n < 4; ++n)
          acc[m][n] = __builtin_amdgcn_mfma_f32_16x16x32_bf16(af[m], bfr[n], acc[m][n], 0, 0, 0);
    }
    __syncthreads();
  }

  // ---- epilogue: C[row][col] = acc + bias[col] ----
  // C/D layout (m89, verified): col = lane&15, row = (lane>>4)*4 + reg
  const int r0 = bm * BM + wm + (lane >> 4) * 4;
  const int c0 = bn * BN + wn + (lane & 15);
#pragma unroll
  for (int n = 0; n < 4; ++n) {
    const int c = c0 + n * 16;
    const float bv = bias[c];
#pragma unroll
    for (int m = 0; m < 4; ++m) {
#pragma unroll
      for (int j = 0; j < 4; ++j) {
        C[(size_t)(r0 + m * 16 + j) * N + c] = acc[m][n][j] + bv;
      }
    }
  }
}

extern "C" void kernel_launch(void* const* d_in, const int* in_sizes, int n_in,
                              void* d_out, int out_size, void* d_ws, size_t ws_size,
                              hipStream_t stream) {
  const float* x = (const float*)d_in[0];     // [8,2048,4096]
  const float* L = (const float*)d_in[1];     // [64,64,64,8]
  const float* R = (const float*)d_in[2];     // [8,64,64,64]
  const float* bias = (const float*)d_in[3];  // [4096]
  float* out = (float*)d_out;                 // [16384,4096]

  __hip_bfloat16* Wb = (__hip_bfloat16*)d_ws;                                   // 33.5 MB
  __hip_bfloat16* Xb = (__hip_bfloat16*)((char*)d_ws + (size_t)4096 * 4096 * 2); // 134 MB

  const long n8 = (long)16384 * 4096 / 8;
  k_cvt_bf16<<<4096, 256, 0, stream>>>(x, Xb, n8);
  k_make_w<<<4096, 256, 0, stream>>>(L, R, Wb);

  dim3 grid(4096 / BN, 16384 / BM);  // (32, 128)
  k_gemm_bt<<<grid, 256, 0, stream>>>(Xb, Wb, bias, out);
}

// Round 2
// 678.206 us; speedup vs baseline: 1.3394x; 1.3394x over previous
//
#include <hip/hip_runtime.h>
#include <hip/hip_bf16.h>

typedef __attribute__((ext_vector_type(8))) short bf16x8;
typedef __attribute__((ext_vector_type(4))) float f32x4;

#define GLDS(g, l) \
  __builtin_amdgcn_global_load_lds((const __attribute__((address_space(1))) void*)(g), \
                                   (__attribute__((address_space(3))) void*)(l), 16, 0, 0)

#define MFMA_BF16 __builtin_amdgcn_mfma_f32_16x16x32_bf16

// ---------------- Kernel 1: X fp32 -> bf16 (vectorized, grid-stride) ----------------
__global__ __launch_bounds__(256) void k_cvt_bf16(const float* __restrict__ x,
                                                  __hip_bfloat16* __restrict__ y,
                                                  long n8) {
  long stride = (long)gridDim.x * blockDim.x;
  for (long i = (long)blockIdx.x * blockDim.x + threadIdx.x; i < n8; i += stride) {
    const float4* xin = reinterpret_cast<const float4*>(x) + i * 2;
    float4 v0 = xin[0];
    float4 v1 = xin[1];
    union { __hip_bfloat16 h[8]; int4 v; } o;
    o.h[0] = __float2bfloat16(v0.x);
    o.h[1] = __float2bfloat16(v0.y);
    o.h[2] = __float2bfloat16(v0.z);
    o.h[3] = __float2bfloat16(v0.w);
    o.h[4] = __float2bfloat16(v1.x);
    o.h[5] = __float2bfloat16(v1.y);
    o.h[6] = __float2bfloat16(v1.z);
    o.h[7] = __float2bfloat16(v1.w);
    *reinterpret_cast<int4*>(y + i * 8) = o.v;
  }
}

// ---------------- Kernel 2: assemble W bf16 ----------------
// W[o][c*64+d] = sum_r L[o*512 + c*8 + r] * R[((r*64+b)*64+c)*64 + d],  b = o & 63
__global__ __launch_bounds__(256) void k_make_w(const float* __restrict__ L,
                                                const float* __restrict__ R,
                                                __hip_bfloat16* __restrict__ W) {
  int o = blockIdx.x;
  int b = o & 63;
  __shared__ float Ls[512];
  Ls[threadIdx.x] = L[(size_t)o * 512 + threadIdx.x];
  Ls[threadIdx.x + 256] = L[(size_t)o * 512 + 256 + threadIdx.x];
  __syncthreads();
  for (int idx = threadIdx.x; idx < 4096; idx += 256) {
    int c = idx >> 6;
    int d = idx & 63;
    float s = 0.f;
#pragma unroll
    for (int r = 0; r < 8; ++r) {
      s += Ls[c * 8 + r] * R[(((size_t)(r * 64 + b) * 64 + c) << 6) + d];
    }
    W[(size_t)o * 4096 + idx] = __float2bfloat16(s);
  }
}

// ---------------- Kernel 3: 256x256 8-phase bf16 GEMM, C = A * B^T + bias ----------------
// A: [16384][4096] bf16 row-major, B: [4096][4096] bf16 row-major (K-contiguous)
// 8 waves (2M x 4N), each owns 128x64. BK=64, double-buffered 128 KiB LDS.
// T2 XOR-swizzle (row&7)<<4 via pre-swizzled global src + swizzled ds_read.
__global__ __launch_bounds__(512, 2) void k_gemm_bt(const __hip_bfloat16* __restrict__ A,
                                                    const __hip_bfloat16* __restrict__ B,
                                                    const float* __restrict__ bias,
                                                    float* __restrict__ C) {
  const int K = 4096, N = 4096, NT = 64;
  __shared__ char lds[131072];
  char* const sA = lds;           // 2 x 32768 (A tile: [256][64] bf16)
  char* const sB = lds + 65536;   // 2 x 32768

  const int tid = threadIdx.x;
  const int lane = tid & 63;
  const int wid = tid >> 6;   // 0..7
  const int wr = wid >> 2;    // 0..1  (M half)
  const int wc = wid & 3;     // 0..3  (N quarter)

  // T1: bijective XCD swizzle (nwg = 1024, divisible by 8)
  const int orig = blockIdx.x;
  const int wg = (orig & 7) * 128 + (orig >> 3);
  const int gm0 = (wg >> 4) * 256;  // bm 0..63
  const int gn0 = (wg & 15) * 256;  // bn 0..15

  // ---- staging geometry (pre-swizzled global source, linear LDS dest) ----
  // chunk P = j*8192 + tid*16 ; logical = P ^ ((P>>7 & 7)<<4)
  const int crow = tid >> 3;                                    // row within 64-row group
  const int scol = ((tid & 7) << 4) ^ ((crow & 7) << 4);        // swizzled byte col in row
  const int wbase = (tid >> 6) << 10;                           // wave-uniform LDS chunk base
  const char* const Abase = (const char*)(A + (size_t)gm0 * K);
  const char* const Bbase = (const char*)(B + (size_t)gn0 * K);

  auto STAGE = [&](int kt, int buf) {
    const size_t cb = (size_t)kt * 2;
#pragma unroll
    for (int j = 0; j < 4; ++j) {
      const int r = (j << 6) + crow;
      GLDS(Abase + (size_t)r * (K * 2) + cb + scol, sA + (buf << 15) + (j << 13) + wbase);
    }
#pragma unroll
    for (int j = 0; j < 4; ++j) {
      const int r = (j << 6) + crow;
      GLDS(Bbase + (size_t)r * (K * 2) + cb + scol, sB + (buf << 15) + (j << 13) + wbase);
    }
  };

  // ---- fragment-read geometry (swizzled ds_read) ----
  const int lr = lane & 15;
  const int lk = lane >> 4;
  const int kx0 = (lk << 4) ^ ((lr & 7) << 4);          // ks=0 byte offset in row
  const int kx1 = (64 + (lk << 4)) ^ ((lr & 7) << 4);   // ks=1
  const int aoff0 = ((wr << 7) + lr) << 7;              // (wr*128 + lr) * 128
  const int boff0 = ((wc << 6) + lr) << 7;              // (wc*64  + lr) * 128

  f32x4 acc[8][4];
#pragma unroll
  for (int m = 0; m < 8; ++m)
#pragma unroll
    for (int n = 0; n < 4; ++n) acc[m][n] = (f32x4){0.f, 0.f, 0.f, 0.f};

  bf16x8 af[4][2], bfv[4][2];

  // ---- prologue: tiles 0 and 1 in flight; wait only tile 0 ----
  STAGE(0, 0);
  STAGE(64, 1);
  asm volatile("s_waitcnt vmcnt(8)" ::: "memory");
  __builtin_amdgcn_sched_barrier(0);
  __builtin_amdgcn_s_barrier();

  int bufc = 0;
  for (int t = 0; t < NT; ++t) {
    char* const cA = sA + (bufc << 15);
    char* const cB = sB + (bufc << 15);

    // ======== phase 1: read A[mh0], B[n0..1]; MFMA quadrant (mh0, nh0) ========
#pragma unroll
    for (int m = 0; m < 4; ++m) {
      af[m][0] = *(const bf16x8*)(cA + aoff0 + m * 2048 + kx0);
      af[m][1] = *(const bf16x8*)(cA + aoff0 + m * 2048 + kx1);
    }
#pragma unroll
    for (int n = 0; n < 2; ++n) {
      bfv[n][0] = *(const bf16x8*)(cB + boff0 + n * 2048 + kx0);
      bfv[n][1] = *(const bf16x8*)(cB + boff0 + n * 2048 + kx1);
    }
    __builtin_amdgcn_s_barrier();
    asm volatile("s_waitcnt lgkmcnt(0)" ::: "memory");
    __builtin_amdgcn_sched_barrier(0);
    __builtin_amdgcn_s_setprio(1);
#pragma unroll
    for (int m = 0; m < 4; ++m)
#pragma unroll
      for (int n = 0; n < 2; ++n) {
        acc[m][n] = MFMA_BF16(af[m][0], bfv[n][0], acc[m][n], 0, 0, 0);
        acc[m][n] = MFMA_BF16(af[m][1], bfv[n][1], acc[m][n], 0, 0, 0);
      }
    __builtin_amdgcn_s_setprio(0);
    __builtin_amdgcn_s_barrier();

    // ======== phase 2: read B[n2..3]; MFMA quadrant (mh0, nh1) ========
#pragma unroll
    for (int n = 2; n < 4; ++n) {
      bfv[n][0] = *(const bf16x8*)(cB + boff0 + n * 2048 + kx0);
      bfv[n][1] = *(const bf16x8*)(cB + boff0 + n * 2048 + kx1);
    }
    __builtin_amdgcn_s_barrier();
    asm volatile("s_waitcnt lgkmcnt(0)" ::: "memory");
    __builtin_amdgcn_sched_barrier(0);
    __builtin_amdgcn_s_setprio(1);
#pragma unroll
    for (int m = 0; m < 4; ++m)
#pragma unroll
      for (int n = 2; n < 4; ++n) {
        acc[m][n] = MFMA_BF16(af[m][0], bfv[n][0], acc[m][n], 0, 0, 0);
        acc[m][n] = MFMA_BF16(af[m][1], bfv[n][1], acc[m][n], 0, 0, 0);
      }
    __builtin_amdgcn_s_setprio(0);
    __builtin_amdgcn_s_barrier();

    // ======== phase 3: read A[mh1]; MFMA quadrant (mh1, nh1) ========
#pragma unroll
    for (int m = 0; m < 4; ++m) {
      af[m][0] = *(const bf16x8*)(cA + aoff0 + (m + 4) * 2048 + kx0);
      af[m][1] = *(const bf16x8*)(cA + aoff0 + (m + 4) * 2048 + kx1);
    }
    __builtin_amdgcn_s_barrier();
    asm volatile("s_waitcnt lgkmcnt(0)" ::: "memory");
    __builtin_amdgcn_sched_barrier(0);
    __builtin_amdgcn_s_setprio(1);
#pragma unroll
    for (int m = 0; m < 4; ++m)
#pragma unroll
      for (int n = 2; n < 4; ++n) {
        acc[m + 4][n] = MFMA_BF16(af[m][0], bfv[n][0], acc[m + 4][n], 0, 0, 0);
        acc[m + 4][n] = MFMA_BF16(af[m][1], bfv[n][1], acc[m + 4][n], 0, 0, 0);
      }
    __builtin_amdgcn_s_setprio(0);
    __builtin_amdgcn_s_barrier();  // after this barrier buf[bufc] is fully consumed

    // ======== phase 4: stage tile t+2 into freed buffer; MFMA quadrant (mh1, nh0) ========
    if (t < NT - 2) STAGE((t + 2) << 6, bufc);
    __builtin_amdgcn_s_setprio(1);
#pragma unroll
    for (int m = 0; m < 4; ++m)
#pragma unroll
      for (int n = 0; n < 2; ++n) {
        acc[m + 4][n] = MFMA_BF16(af[m][0], bfv[n][0], acc[m + 4][n], 0, 0, 0);
        acc[m + 4][n] = MFMA_BF16(af[m][1], bfv[n][1], acc[m + 4][n], 0, 0, 0);
      }
    __builtin_amdgcn_s_setprio(0);
    if (t < NT - 2) {
      asm volatile("s_waitcnt vmcnt(8)" ::: "memory");   // tile t+1 landed; t+2 in flight
    } else if (t == NT - 2) {
      asm volatile("s_waitcnt vmcnt(0)" ::: "memory");   // epilogue drain
    }
    __builtin_amdgcn_sched_barrier(0);
    __builtin_amdgcn_s_barrier();
    bufc ^= 1;
  }

  // ---- epilogue: C[row][col] = acc + bias[col] ----
  // C/D layout (verified r1): col = lane&15, row = (lane>>4)*4 + j
  const int er = gm0 + (wr << 7) + ((lane >> 4) << 2);
  const int ec = gn0 + (wc << 6) + (lane & 15);
#pragma unroll
  for (int n = 0; n < 4; ++n) {
    const int c = ec + n * 16;
    const float bv = bias[c];
#pragma unroll
    for (int m = 0; m < 8; ++m) {
#pragma unroll
      for (int j = 0; j < 4; ++j) {
        C[(size_t)(er + m * 16 + j) * N + c] = acc[m][n][j] + bv;
      }
    }
  }
}

extern "C" void kernel_launch(void* const* d_in, const int* in_sizes, int n_in,
                              void* d_out, int out_size, void* d_ws, size_t ws_size,
                              hipStream_t stream) {
  const float* x = (const float*)d_in[0];     // [8,2048,4096]
  const float* L = (const float*)d_in[1];     // [64,64,64,8]
  const float* R = (const float*)d_in[2];     // [8,64,64,64]
  const float* bias = (const float*)d_in[3];  // [4096]
  float* out = (float*)d_out;                 // [16384,4096]

  __hip_bfloat16* Wb = (__hip_bfloat16*)d_ws;                                    // 33.5 MB
  __hip_bfloat16* Xb = (__hip_bfloat16*)((char*)d_ws + (size_t)4096 * 4096 * 2); // 134 MB

  const long n8 = (long)16384 * 4096 / 8;
  k_cvt_bf16<<<4096, 256, 0, stream>>>(x, Xb, n8);
  k_make_w<<<4096, 256, 0, stream>>>(L, R, Wb);

  dim3 grid(1024);  // (16384/256) * (4096/256)
  k_gemm_bt<<<grid, 512, 0, stream>>>(Xb, Wb, bias, out);
}

// Round 3
// 570.649 us; speedup vs baseline: 1.5918x; 1.1885x over previous
//
#include <hip/hip_runtime.h>
#include <hip/hip_bf16.h>

typedef __attribute__((ext_vector_type(8))) short bf16x8;
typedef __attribute__((ext_vector_type(4))) float f32x4;

#define GLDS(g, l) \
  __builtin_amdgcn_global_load_lds((const __attribute__((address_space(1))) void*)(g), \
                                   (__attribute__((address_space(3))) void*)(l), 16, 0, 0)

#define MFMA_BF16 __builtin_amdgcn_mfma_f32_16x16x32_bf16

// ---------------- Kernel 1: X fp32 -> bf16 (vectorized, grid-stride) ----------------
__global__ __launch_bounds__(256) void k_cvt_bf16(const float* __restrict__ x,
                                                  __hip_bfloat16* __restrict__ y,
                                                  long n8) {
  long stride = (long)gridDim.x * blockDim.x;
  for (long i = (long)blockIdx.x * blockDim.x + threadIdx.x; i < n8; i += stride) {
    const float4* xin = reinterpret_cast<const float4*>(x) + i * 2;
    float4 v0 = xin[0];
    float4 v1 = xin[1];
    union { __hip_bfloat16 h[8]; int4 v; } o;
    o.h[0] = __float2bfloat16(v0.x);
    o.h[1] = __float2bfloat16(v0.y);
    o.h[2] = __float2bfloat16(v0.z);
    o.h[3] = __float2bfloat16(v0.w);
    o.h[4] = __float2bfloat16(v1.x);
    o.h[5] = __float2bfloat16(v1.y);
    o.h[6] = __float2bfloat16(v1.z);
    o.h[7] = __float2bfloat16(v1.w);
    *reinterpret_cast<int4*>(y + i * 8) = o.v;
  }
}

// ---------------- Kernel 2: assemble W bf16 ----------------
__global__ __launch_bounds__(256) void k_make_w(const float* __restrict__ L,
                                                const float* __restrict__ R,
                                                __hip_bfloat16* __restrict__ W) {
  int o = blockIdx.x;
  int b = o & 63;
  __shared__ float Ls[512];
  Ls[threadIdx.x] = L[(size_t)o * 512 + threadIdx.x];
  Ls[threadIdx.x + 256] = L[(size_t)o * 512 + 256 + threadIdx.x];
  __syncthreads();
  for (int idx = threadIdx.x; idx < 4096; idx += 256) {
    int c = idx >> 6;
    int d = idx & 63;
    float s = 0.f;
#pragma unroll
    for (int r = 0; r < 8; ++r) {
      s += Ls[c * 8 + r] * R[(((size_t)(r * 64 + b) * 64 + c) << 6) + d];
    }
    W[(size_t)o * 4096 + idx] = __float2bfloat16(s);
  }
}

// ---------------- Kernel 3: 256x256 8-phase bf16 GEMM, C = A * B^T + bias ----------------
// Fine-interleaved schedule (m196/m201): 1 half-tile (2 gload_lds) issued per phase,
// one counted vmcnt(4) per K-tile at P4. T2 swizzle + T1 XCD swizzle + T5 setprio.
__global__ __launch_bounds__(512, 2) void k_gemm_bt(const __hip_bfloat16* __restrict__ A,
                                                    const __hip_bfloat16* __restrict__ B,
                                                    const float* __restrict__ bias,
                                                    float* __restrict__ C) {
  const int K = 4096, N = 4096, NT = 64;
  __shared__ char lds[131072];
  char* const sA = lds;           // 2 x 32768 (A tile: [256][64] bf16; half h = rows h*128..)
  char* const sB = lds + 65536;   // 2 x 32768

  const int tid = threadIdx.x;
  const int lane = tid & 63;
  const int wid = tid >> 6;   // 0..7
  const int wr = wid >> 2;    // 0..1  (M half)
  const int wc = wid & 3;     // 0..3  (N quarter)

  // T1: bijective XCD swizzle (nwg = 1024, divisible by 8)
  const int orig = blockIdx.x;
  const int wg = (orig & 7) * 128 + (orig >> 3);
  const int gm0 = (wg >> 4) * 256;
  const int gn0 = (wg & 15) * 256;

  // ---- staging geometry (pre-swizzled global source, linear LDS dest) ----
  const int crow = tid >> 3;                              // row within 64-row group
  const int scol = ((tid & 7) << 4) ^ ((crow & 7) << 4);  // swizzled byte col in row
  const int wbase = (tid >> 6) << 10;                     // wave-uniform LDS chunk base
  const char* const Abase = (const char*)(A + (size_t)gm0 * K);
  const char* const Bbase = (const char*)(B + (size_t)gn0 * K);

  // half h of a 256-row tile = 64-row groups j = 2h, 2h+1 ; 2 gload_lds per half
  auto STAGE_A_HALF = [&](int buf, int h, int kt) {
#pragma unroll
    for (int i = 0; i < 2; ++i) {
      const int j = (h << 1) + i;
      const int r = (j << 6) + crow;
      GLDS(Abase + (size_t)r * (K * 2) + (size_t)kt * 2 + scol,
           sA + (buf << 15) + (j << 13) + wbase);
    }
  };
  auto STAGE_B_HALF = [&](int buf, int h, int kt) {
#pragma unroll
    for (int i = 0; i < 2; ++i) {
      const int j = (h << 1) + i;
      const int r = (j << 6) + crow;
      GLDS(Bbase + (size_t)r * (K * 2) + (size_t)kt * 2 + scol,
           sB + (buf << 15) + (j << 13) + wbase);
    }
  };

  // ---- fragment-read geometry (swizzled ds_read) ----
  const int lr = lane & 15;
  const int lk = lane >> 4;
  const int kx0 = (lk << 4) ^ ((lr & 7) << 4);
  const int kx1 = (64 + (lk << 4)) ^ ((lr & 7) << 4);
  const int aoff0 = ((wr << 7) + lr) << 7;   // (wr*128 + lr) * 128B
  const int boff0 = ((wc << 6) + lr) << 7;   // (wc*64  + lr) * 128B

  f32x4 acc[8][4];
#pragma unroll
  for (int m = 0; m < 8; ++m)
#pragma unroll
    for (int n = 0; n < 4; ++n) acc[m][n] = (f32x4){0.f, 0.f, 0.f, 0.f};

  bf16x8 af[4][2], bfv[4][2];

  // ---- prologue: tile0 (8 loads) + B(1) (4 loads); wait tile0 only ----
  STAGE_A_HALF(0, 0, 0);
  STAGE_A_HALF(0, 1, 0);
  STAGE_B_HALF(0, 0, 0);
  STAGE_B_HALF(0, 1, 0);
  STAGE_B_HALF(1, 0, 64);
  STAGE_B_HALF(1, 1, 64);
  asm volatile("s_waitcnt vmcnt(4)" ::: "memory");
  __builtin_amdgcn_sched_barrier(0);
  __builtin_amdgcn_s_barrier();

  int bufc = 0;
  for (int t = 0; t < NT; ++t) {
    char* const cA = sA + (bufc << 15);
    char* const cB = sB + (bufc << 15);
    const int nb = bufc ^ 1;

    // ======== P1: read A[m0-3] + B[n0-1]; stage Ah0(t+1)->nb; MFMA (m0-3, n0-1) ========
#pragma unroll
    for (int m = 0; m < 4; ++m) {
      af[m][0] = *(const bf16x8*)(cA + aoff0 + m * 2048 + kx0);
      af[m][1] = *(const bf16x8*)(cA + aoff0 + m * 2048 + kx1);
    }
#pragma unroll
    for (int n = 0; n < 2; ++n) {
      bfv[n][0] = *(const bf16x8*)(cB + boff0 + n * 2048 + kx0);
      bfv[n][1] = *(const bf16x8*)(cB + boff0 + n * 2048 + kx1);
    }
    if (t + 1 < NT) STAGE_A_HALF(nb, 0, (t + 1) << 6);
    __builtin_amdgcn_s_barrier();
    asm volatile("s_waitcnt lgkmcnt(0)" ::: "memory");
    __builtin_amdgcn_sched_barrier(0);
    __builtin_amdgcn_s_setprio(1);
#pragma unroll
    for (int m = 0; m < 4; ++m)
#pragma unroll
      for (int n = 0; n < 2; ++n) {
        acc[m][n] = MFMA_BF16(af[m][0], bfv[n][0], acc[m][n], 0, 0, 0);
        acc[m][n] = MFMA_BF16(af[m][1], bfv[n][1], acc[m][n], 0, 0, 0);
      }
    __builtin_amdgcn_s_setprio(0);
    __builtin_amdgcn_s_barrier();

    // ======== P2: read B[n2-3]; stage Ah1(t+1)->nb; MFMA (m0-3, n2-3) ========
#pragma unroll
    for (int n = 2; n < 4; ++n) {
      bfv[n][0] = *(const bf16x8*)(cB + boff0 + n * 2048 + kx0);
      bfv[n][1] = *(const bf16x8*)(cB + boff0 + n * 2048 + kx1);
    }
    if (t + 1 < NT) STAGE_A_HALF(nb, 1, (t + 1) << 6);
    __builtin_amdgcn_s_barrier();
    asm volatile("s_waitcnt lgkmcnt(0)" ::: "memory");
    __builtin_amdgcn_sched_barrier(0);
    __builtin_amdgcn_s_setprio(1);
#pragma unroll
    for (int m = 0; m < 4; ++m)
#pragma unroll
      for (int n = 2; n < 4; ++n) {
        acc[m][n] = MFMA_BF16(af[m][0], bfv[n][0], acc[m][n], 0, 0, 0);
        acc[m][n] = MFMA_BF16(af[m][1], bfv[n][1], acc[m][n], 0, 0, 0);
      }
    __builtin_amdgcn_s_setprio(0);
    __builtin_amdgcn_s_barrier();

    // ======== P3: read A[m4-7]; stage Bh0(t+2)->bufc (freed after P2); MFMA (m4-7, n2-3) ========
#pragma unroll
    for (int m = 0; m < 4; ++m) {
      af[m][0] = *(const bf16x8*)(cA + aoff0 + (m + 4) * 2048 + kx0);
      af[m][1] = *(const bf16x8*)(cA + aoff0 + (m + 4) * 2048 + kx1);
    }
    if (t + 2 < NT) STAGE_B_HALF(bufc, 0, (t + 2) << 6);
    __builtin_amdgcn_s_barrier();
    asm volatile("s_waitcnt lgkmcnt(0)" ::: "memory");
    __builtin_amdgcn_sched_barrier(0);
    __builtin_amdgcn_s_setprio(1);
#pragma unroll
    for (int m = 0; m < 4; ++m)
#pragma unroll
      for (int n = 2; n < 4; ++n) {
        acc[m + 4][n] = MFMA_BF16(af[m][0], bfv[n][0], acc[m + 4][n], 0, 0, 0);
        acc[m + 4][n] = MFMA_BF16(af[m][1], bfv[n][1], acc[m + 4][n], 0, 0, 0);
      }
    __builtin_amdgcn_s_setprio(0);
    __builtin_amdgcn_s_barrier();

    // ======== P4: stage Bh1(t+2)->bufc; MFMA (m4-7, n0-1); counted wait ========
    if (t + 2 < NT) STAGE_B_HALF(bufc, 1, (t + 2) << 6);
    __builtin_amdgcn_s_setprio(1);
#pragma unroll
    for (int m = 0; m < 4; ++m)
#pragma unroll
      for (int n = 0; n < 2; ++n) {
        acc[m + 4][n] = MFMA_BF16(af[m][0], bfv[n][0], acc[m + 4][n], 0, 0, 0);
        acc[m + 4][n] = MFMA_BF16(af[m][1], bfv[n][1], acc[m + 4][n], 0, 0, 0);
      }
    __builtin_amdgcn_s_setprio(0);
    if (t < NT - 2) {
      // outstanding: A(t+1)[4] + B(t+2)[4] = 8 -> drain A(t+1), keep B(t+2) in flight
      asm volatile("s_waitcnt vmcnt(4)" ::: "memory");
    } else if (t == NT - 2) {
      asm volatile("s_waitcnt vmcnt(0)" ::: "memory");  // drain A(NT-1)
    }
    __builtin_amdgcn_sched_barrier(0);
    __builtin_amdgcn_s_barrier();
    bufc ^= 1;
  }

  // ---- epilogue: C[row][col] = acc + bias[col] ----
  const int er = gm0 + (wr << 7) + ((lane >> 4) << 2);
  const int ec = gn0 + (wc << 6) + (lane & 15);
#pragma unroll
  for (int n = 0; n < 4; ++n) {
    const int c = ec + n * 16;
    const float bv = bias[c];
#pragma unroll
    for (int m = 0; m < 8; ++m) {
#pragma unroll
      for (int j = 0; j < 4; ++j) {
        C[(size_t)(er + m * 16 + j) * N + c] = acc[m][n][j] + bv;
      }
    }
  }
}

extern "C" void kernel_launch(void* const* d_in, const int* in_sizes, int n_in,
                              void* d_out, int out_size, void* d_ws, size_t ws_size,
                              hipStream_t stream) {
  const float* x = (const float*)d_in[0];     // [8,2048,4096]
  const float* L = (const float*)d_in[1];     // [64,64,64,8]
  const float* R = (const float*)d_in[2];     // [8,64,64,64]
  const float* bias = (const float*)d_in[3];  // [4096]
  float* out = (float*)d_out;                 // [16384,4096]

  __hip_bfloat16* Wb = (__hip_bfloat16*)d_ws;                                    // 33.5 MB
  __hip_bfloat16* Xb = (__hip_bfloat16*)((char*)d_ws + (size_t)4096 * 4096 * 2); // 134 MB

  const long n8 = (long)16384 * 4096 / 8;
  k_cvt_bf16<<<4096, 256, 0, stream>>>(x, Xb, n8);
  k_make_w<<<4096, 256, 0, stream>>>(L, R, Wb);

  dim3 grid(1024);  // (16384/256) * (4096/256)
  k_gemm_bt<<<grid, 512, 0, stream>>>(Xb, Wb, bias, out);
}